// Round 1
// baseline (14509.224 us; speedup 1.0000x reference)
//
#include <hip/hip_runtime.h>
#include <hip/hip_bf16.h>

typedef float f32x4 __attribute__((ext_vector_type(4)));
typedef __bf16 bf16x8 __attribute__((ext_vector_type(8)));

#define B_SZ 2048
#define T_IN 48
#define FEAT 64
#define UNITS 1024
#define GCOLS 4096   // 4*UNITS, gate-interleaved columns: col = 4*unit + gate
#define OUT_STEPS 64
#define KWARM 1088   // UNITS + FEAT

typedef __attribute__((address_space(1))) const void gas_t;
typedef __attribute__((address_space(3))) void las_t;

__device__ __forceinline__ void gl_lds16(const void* g, void* l) {
    __builtin_amdgcn_global_load_lds((gas_t*)g, (las_t*)l, 16, 0, 0);
}
__device__ __forceinline__ float sigm(float x) { return 1.0f / (1.0f + __expf(-x)); }
__device__ __forceinline__ float tanh_fast(float x) {
    float e = __expf(2.0f * x);
    return 1.0f - 2.0f / (e + 1.0f);   // exact tanh given exact exp; safe at +/-inf
}

// ---------- precompute kernels ----------

// UTw[c'][k] (bf16, [4096][1088]): k<1024 -> U[k][oc], else W[k-1024][oc], oc = gate*1024+unit, c' = 4*unit+gate
__global__ __launch_bounds__(256) void reorder_UW(const float* __restrict__ U, const float* __restrict__ W,
                                                  __hip_bfloat16* __restrict__ UTw) {
    __shared__ __hip_bfloat16 t[64][64];
    const int k0 = blockIdx.x * 64;   // 17 tiles
    const int c0 = blockIdx.y * 64;   // 64 tiles
    const int tid = threadIdx.x;
#pragma unroll
    for (int i = 0; i < 16; ++i) {
        int idx = tid + i * 256;
        int rk = idx >> 6, cc = idx & 63;
        int k = k0 + rk, c = c0 + cc;
        int oc = (c & 3) * UNITS + (c >> 2);
        float v = (k < UNITS) ? U[(size_t)k * GCOLS + oc] : W[(size_t)(k - UNITS) * GCOLS + oc];
        t[rk][cc] = __float2bfloat16(v);
    }
    __syncthreads();
#pragma unroll
    for (int i = 0; i < 16; ++i) {
        int idx = tid + i * 256;
        int rc = idx >> 6, kk = idx & 63;
        UTw[(size_t)(c0 + rc) * KWARM + k0 + kk] = t[kk][rc];
    }
}

// WdT[f][k] (bf16, [64][1024]) = Wd[k][f]
__global__ __launch_bounds__(256) void transpose_Wd(const float* __restrict__ Wd, __hip_bfloat16* __restrict__ WdT) {
    __shared__ __hip_bfloat16 t[64][64];
    const int k0 = blockIdx.x * 64;  // 16 blocks
    const int tid = threadIdx.x;
#pragma unroll
    for (int i = 0; i < 16; ++i) {
        int idx = tid + i * 256;
        int rk = idx >> 6, ff = idx & 63;
        t[rk][ff] = __float2bfloat16(Wd[(size_t)(k0 + rk) * FEAT + ff]);
    }
    __syncthreads();
#pragma unroll
    for (int i = 0; i < 16; ++i) {
        int idx = tid + i * 256;
        int rf = idx >> 6, kk = idx & 63;
        WdT[(size_t)rf * UNITS + k0 + kk] = t[kk][rf];
    }
}

// UTd[c'][k] (bf16, [4096][1024]) = U-part(UTw) + sum_f Wd[k][f] * W[f][oc(c')]
__global__ __launch_bounds__(256) void build_UTdec(const __hip_bfloat16* __restrict__ UTw,
                                                   const __hip_bfloat16* __restrict__ WdT,
                                                   __hip_bfloat16* __restrict__ UTd) {
    __shared__ float Wl[64][16];
    const int k = blockIdx.x * 256 + threadIdx.x;  // 4 blocks
    const int c0 = blockIdx.y * 16;                // 256 blocks
    const int tid = threadIdx.x;
#pragma unroll
    for (int i = 0; i < 4; ++i) {
        int idx = tid + i * 256;
        int f = idx >> 4, cc = idx & 15;
        Wl[f][cc] = __bfloat162float(UTw[(size_t)(c0 + cc) * KWARM + UNITS + f]);
    }
    __syncthreads();
    float acc[16];
#pragma unroll
    for (int cc = 0; cc < 16; ++cc) acc[cc] = 0.f;
    for (int f = 0; f < 64; ++f) {
        float wd = __bfloat162float(WdT[(size_t)f * UNITS + k]);
#pragma unroll
        for (int cc = 0; cc < 16; ++cc) acc[cc] += wd * Wl[f][cc];
    }
#pragma unroll
    for (int cc = 0; cc < 16; ++cc) {
        float uv = __bfloat162float(UTw[(size_t)(c0 + cc) * KWARM + k]);
        UTd[(size_t)(c0 + cc) * UNITS + k] = __float2bfloat16(uv + acc[cc]);
    }
}

// bw[c'] = b[oc]; bdc[c'] = b[oc] + sum_f bd[f]*W[f][oc]
__global__ __launch_bounds__(256) void build_bias(const float* __restrict__ b, const float* __restrict__ bd,
                                                  const __hip_bfloat16* __restrict__ UTw,
                                                  float* __restrict__ bw, float* __restrict__ bdc) {
    const int c = blockIdx.x * 256 + threadIdx.x;  // 16 blocks
    const int oc = (c & 3) * UNITS + (c >> 2);
    float base = b[oc];
    float s = 0.f;
    for (int f = 0; f < FEAT; ++f) s += bd[f] * __bfloat162float(UTw[(size_t)c * KWARM + UNITS + f]);
    bw[c] = base;
    bdc[c] = base + s;
}

__global__ void convert_x(const float* __restrict__ x, __hip_bfloat16* __restrict__ xb, int n) {
    int i = blockIdx.x * blockDim.x + threadIdx.x;
    if (i < n) xb[i] = __float2bfloat16(x[i]);
}

// ---------- fused LSTM step ----------
// Z[2048][4096(interleaved)] = [h | x_t] @ UT^T + bias ; gates -> c,h update in epilogue.
// PRED: nb==0 blocks also compute pred_{t} = h_in @ Wd + bd into out[:, tstep, :].
template <bool WARM, bool PRED>
__global__ __launch_bounds__(256) void lstm_step(
    const __hip_bfloat16* __restrict__ hin,          // [2048][1024]
    const __hip_bfloat16* __restrict__ xbf, int t,   // [2048][48][64] (WARM only)
    const __hip_bfloat16* __restrict__ UT, int Kdim, // [4096][Kdim]
    const float* __restrict__ bias,                  // [4096]
    float* __restrict__ cst,                         // [2048][1024]
    __hip_bfloat16* __restrict__ hout,               // [2048][1024]
    const __hip_bfloat16* __restrict__ WdT,          // [64][1024] (PRED)
    const float* __restrict__ bd,                    // [64] (PRED)
    float* __restrict__ out, int tstep)              // [2048][64][64] (PRED)
{
    __shared__ alignas(16) __hip_bfloat16 Al[128 * 64];
    __shared__ alignas(16) __hip_bfloat16 Bl[128 * 64];
    __shared__ alignas(16) __hip_bfloat16 Wl[PRED ? 64 * 64 : 8];

    const int tid = threadIdx.x;
    const int lane = tid & 63;
    const int wv = tid >> 6;
    const int wr = wv >> 1, wc = wv & 1;
    const int bid = blockIdx.x;
    const int nb = bid & 31;   // 32 n-tiles
    const int mb = bid >> 5;   // 16 m-tiles
    const int m0 = mb * 128;
    const int n0 = nb * 128;
    const bool doPred = PRED && (nb == 0);

    f32x4 acc[4][4] = {};
    f32x4 accp[2][4] = {};

    const int nkt = Kdim >> 6;
    const int lrow = lane >> 3;            // 0..7 row within 8-row chunk
    const int lcol16 = (lane & 7) * 16;    // byte offset within 128B row

    for (int kt = 0; kt < nkt; ++kt) {
        const int k0 = kt * 64;
        // stage A (h rows, or x_t rows for the warmup tail tile)
#pragma unroll
        for (int r = 0; r < 4; ++r) {
            int chunk = r * 4 + wv;
            int row = chunk * 8 + lrow;
            const char* src;
            if (WARM && k0 >= UNITS) {
                src = (const char*)xbf + (size_t)(m0 + row) * (T_IN * FEAT * 2) + (size_t)t * (FEAT * 2) + lcol16;
            } else {
                src = (const char*)hin + (size_t)(m0 + row) * (UNITS * 2) + (size_t)k0 * 2 + lcol16;
            }
            gl_lds16(src, (char*)Al + chunk * 1024);
        }
        // stage B (UT rows = output columns)
#pragma unroll
        for (int r = 0; r < 4; ++r) {
            int chunk = r * 4 + wv;
            int row = chunk * 8 + lrow;
            const char* src = (const char*)UT + (size_t)(n0 + row) * ((size_t)Kdim * 2) + (size_t)k0 * 2 + lcol16;
            gl_lds16(src, (char*)Bl + chunk * 1024);
        }
        if (doPred) {
#pragma unroll
            for (int r = 0; r < 2; ++r) {
                int chunk = r * 4 + wv;
                int row = chunk * 8 + lrow;
                const char* src = (const char*)WdT + (size_t)row * (UNITS * 2) + (size_t)k0 * 2 + lcol16;
                gl_lds16(src, (char*)Wl + chunk * 1024);
            }
        }
        __syncthreads();

        const int ar = lane & 15;
        const int ko = (lane >> 4) << 3;
#pragma unroll
        for (int kk = 0; kk < 2; ++kk) {
            bf16x8 af[4], bfr[4];
#pragma unroll
            for (int mi = 0; mi < 4; ++mi)
                af[mi] = *reinterpret_cast<const bf16x8*>(&Al[(64 * wr + 16 * mi + ar) * 64 + 32 * kk + ko]);
#pragma unroll
            for (int ni = 0; ni < 4; ++ni)
                bfr[ni] = *reinterpret_cast<const bf16x8*>(&Bl[(64 * wc + 16 * ni + ar) * 64 + 32 * kk + ko]);
#pragma unroll
            for (int mi = 0; mi < 4; ++mi)
#pragma unroll
                for (int ni = 0; ni < 4; ++ni)
                    acc[mi][ni] = __builtin_amdgcn_mfma_f32_16x16x32_bf16(af[mi], bfr[ni], acc[mi][ni], 0, 0, 0);
            if (doPred) {
#pragma unroll
                for (int ni = 0; ni < 4; ++ni) {
                    bf16x8 bp = *reinterpret_cast<const bf16x8*>(&Wl[(16 * ni + ar) * 64 + 32 * kk + ko]);
#pragma unroll
                    for (int pi = 0; pi < 2; ++pi)
                        accp[pi][ni] = __builtin_amdgcn_mfma_f32_16x16x32_bf16(af[2 * wc + pi], bp, accp[pi][ni], 0, 0, 0);
                }
            }
        }
        __syncthreads();
    }

    // ---- gate epilogue: cols interleaved 4u+gate; quad shuffle collects i,f,g,o ----
    const int g = lane & 3;
    const int rowb = m0 + 64 * wr + ((lane >> 4) << 2);
#pragma unroll
    for (int ni = 0; ni < 4; ++ni) {
        const int col = n0 + 64 * wc + 16 * ni + (lane & 15);
        const float bv = bias[col];
        const int unit = col >> 2;
#pragma unroll
        for (int mi = 0; mi < 4; ++mi) {
            f32x4 v = acc[mi][ni];
#pragma unroll
            for (int reg = 0; reg < 4; ++reg) {
                float z = v[reg] + bv;
                float z1 = __shfl_xor(z, 1);
                float z2 = __shfl_xor(z, 2);
                float z3 = __shfl_xor(z, 3);
                float zi, zf, zg, zo;
                if (g == 0)      { zi = z;  zf = z1; zg = z2; zo = z3; }
                else if (g == 1) { zi = z1; zf = z;  zg = z3; zo = z2; }
                else if (g == 2) { zi = z2; zf = z3; zg = z;  zo = z1; }
                else             { zi = z3; zf = z2; zg = z1; zo = z;  }
                if (g == reg) {
                    const size_t idx = (size_t)(rowb + 16 * mi + reg) * UNITS + unit;
                    float cn = sigm(zf) * cst[idx] + sigm(zi) * tanh_fast(zg);
                    cst[idx] = cn;
                    hout[idx] = __float2bfloat16(sigm(zo) * tanh_fast(cn));
                }
            }
        }
    }

    if (doPred) {
#pragma unroll
        for (int ni = 0; ni < 4; ++ni) {
            const int f = 16 * ni + (lane & 15);
            const float bdv = bd[f];
#pragma unroll
            for (int pi = 0; pi < 2; ++pi) {
                const int prow = m0 + 64 * wr + 32 * wc + 16 * pi + ((lane >> 4) << 2);
                f32x4 v = accp[pi][ni];
#pragma unroll
                for (int reg = 0; reg < 4; ++reg) {
                    out[(size_t)(prow + reg) * (OUT_STEPS * FEAT) + (size_t)tstep * FEAT + f] = v[reg] + bdv;
                }
            }
        }
    }
}

// ---------- host ----------
extern "C" void kernel_launch(void* const* d_in, const int* in_sizes, int n_in,
                              void* d_out, int out_size, void* d_ws, size_t ws_size,
                              hipStream_t stream) {
    const float* inputs = (const float*)d_in[0];
    const float* W  = (const float*)d_in[1];
    const float* U  = (const float*)d_in[2];
    const float* b  = (const float*)d_in[3];
    const float* Wd = (const float*)d_in[4];
    const float* bd = (const float*)d_in[5];
    float* out = (float*)d_out;

    char* ws = (char*)d_ws;
    size_t off = 0;
    auto alloc = [&](size_t bytes) { char* p = ws + off; off = (off + bytes + 255) & ~255ULL; return p; };
    __hip_bfloat16* UTw = (__hip_bfloat16*)alloc((size_t)GCOLS * KWARM * 2);
    __hip_bfloat16* UTd = (__hip_bfloat16*)alloc((size_t)GCOLS * UNITS * 2);
    __hip_bfloat16* WdT = (__hip_bfloat16*)alloc((size_t)FEAT * UNITS * 2);
    __hip_bfloat16* Xbf = (__hip_bfloat16*)alloc((size_t)B_SZ * T_IN * FEAT * 2);
    __hip_bfloat16* hA  = (__hip_bfloat16*)alloc((size_t)B_SZ * UNITS * 2);
    __hip_bfloat16* hB  = (__hip_bfloat16*)alloc((size_t)B_SZ * UNITS * 2);
    float* cst = (float*)alloc((size_t)B_SZ * UNITS * 4);
    float* bw  = (float*)alloc(GCOLS * 4);
    float* bdc = (float*)alloc(GCOLS * 4);

    hipMemsetAsync(cst, 0, (size_t)B_SZ * UNITS * 4, stream);
    hipMemsetAsync(hA, 0, (size_t)B_SZ * UNITS * 2, stream);

    dim3 blk(256);
    reorder_UW<<<dim3(17, 64), blk, 0, stream>>>(U, W, UTw);
    transpose_Wd<<<dim3(16), blk, 0, stream>>>(Wd, WdT);
    build_UTdec<<<dim3(4, 256), blk, 0, stream>>>(UTw, WdT, UTd);
    build_bias<<<dim3(16), blk, 0, stream>>>(b, bd, UTw, bw, bdc);
    {
        int n = B_SZ * T_IN * FEAT;
        convert_x<<<dim3((n + 255) / 256), blk, 0, stream>>>(inputs, Xbf, n);
    }

    const __hip_bfloat16* cur = hA;
    __hip_bfloat16* nxt = hB;
    for (int t = 0; t < T_IN; ++t) {
        lstm_step<true, false><<<dim3(512), blk, 0, stream>>>(cur, Xbf, t, UTw, KWARM, bw, cst, nxt,
                                                              nullptr, nullptr, nullptr, 0);
        __hip_bfloat16* tmp = (__hip_bfloat16*)cur; cur = nxt; nxt = tmp;
    }
    // decode: kernel t consumes h_{t-1} (writes pred_{t-1}) and produces h_t
    for (int t = 1; t <= OUT_STEPS; ++t) {
        lstm_step<false, true><<<dim3(512), blk, 0, stream>>>(cur, nullptr, 0, UTd, UNITS, bdc, cst, nxt,
                                                              WdT, bd, out, t - 1);
        __hip_bfloat16* tmp = (__hip_bfloat16*)cur; cur = nxt; nxt = tmp;
    }
}

// Round 2
// 8499.603 us; speedup vs baseline: 1.7070x; 1.7070x over previous
//
#include <hip/hip_runtime.h>
#include <hip/hip_bf16.h>

typedef float f32x4 __attribute__((ext_vector_type(4)));
typedef __bf16 bf16x8 __attribute__((ext_vector_type(8)));

#define B_SZ 2048
#define T_IN 48
#define FEAT 64
#define UNITS 1024
#define GCOLS 4096   // 4*UNITS, gate-interleaved columns: col = 4*unit + gate
#define OUT_STEPS 64
#define KWARM 1088   // UNITS + FEAT

typedef __attribute__((address_space(1))) const void gas_t;
typedef __attribute__((address_space(3))) void las_t;

__device__ __forceinline__ void gl_lds16(const void* g, void* l) {
    __builtin_amdgcn_global_load_lds((gas_t*)g, (las_t*)l, 16, 0, 0);
}
__device__ __forceinline__ float sigm(float x) { return 1.0f / (1.0f + __expf(-x)); }
__device__ __forceinline__ float tanh_fast(float x) {
    float e = __expf(2.0f * x);
    return 1.0f - 2.0f / (e + 1.0f);   // exact tanh given exact exp; safe at +/-inf
}

// ---------- precompute kernels (unchanged from R1, correctness-proven) ----------

__global__ __launch_bounds__(256) void reorder_UW(const float* __restrict__ U, const float* __restrict__ W,
                                                  __hip_bfloat16* __restrict__ UTw) {
    __shared__ __hip_bfloat16 t[64][64];
    const int k0 = blockIdx.x * 64;   // 17 tiles
    const int c0 = blockIdx.y * 64;   // 64 tiles
    const int tid = threadIdx.x;
#pragma unroll
    for (int i = 0; i < 16; ++i) {
        int idx = tid + i * 256;
        int rk = idx >> 6, cc = idx & 63;
        int k = k0 + rk, c = c0 + cc;
        int oc = (c & 3) * UNITS + (c >> 2);
        float v = (k < UNITS) ? U[(size_t)k * GCOLS + oc] : W[(size_t)(k - UNITS) * GCOLS + oc];
        t[rk][cc] = __float2bfloat16(v);
    }
    __syncthreads();
#pragma unroll
    for (int i = 0; i < 16; ++i) {
        int idx = tid + i * 256;
        int rc = idx >> 6, kk = idx & 63;
        UTw[(size_t)(c0 + rc) * KWARM + k0 + kk] = t[kk][rc];
    }
}

__global__ __launch_bounds__(256) void transpose_Wd(const float* __restrict__ Wd, __hip_bfloat16* __restrict__ WdT) {
    __shared__ __hip_bfloat16 t[64][64];
    const int k0 = blockIdx.x * 64;  // 16 blocks
    const int tid = threadIdx.x;
#pragma unroll
    for (int i = 0; i < 16; ++i) {
        int idx = tid + i * 256;
        int rk = idx >> 6, ff = idx & 63;
        t[rk][ff] = __float2bfloat16(Wd[(size_t)(k0 + rk) * FEAT + ff]);
    }
    __syncthreads();
#pragma unroll
    for (int i = 0; i < 16; ++i) {
        int idx = tid + i * 256;
        int rf = idx >> 6, kk = idx & 63;
        WdT[(size_t)rf * UNITS + k0 + kk] = t[kk][rf];
    }
}

__global__ __launch_bounds__(256) void build_UTdec(const __hip_bfloat16* __restrict__ UTw,
                                                   const __hip_bfloat16* __restrict__ WdT,
                                                   __hip_bfloat16* __restrict__ UTd) {
    __shared__ float Wl[64][16];
    const int k = blockIdx.x * 256 + threadIdx.x;  // 4 blocks
    const int c0 = blockIdx.y * 16;                // 256 blocks
    const int tid = threadIdx.x;
#pragma unroll
    for (int i = 0; i < 4; ++i) {
        int idx = tid + i * 256;
        int f = idx >> 4, cc = idx & 15;
        Wl[f][cc] = __bfloat162float(UTw[(size_t)(c0 + cc) * KWARM + UNITS + f]);
    }
    __syncthreads();
    float acc[16];
#pragma unroll
    for (int cc = 0; cc < 16; ++cc) acc[cc] = 0.f;
    for (int f = 0; f < 64; ++f) {
        float wd = __bfloat162float(WdT[(size_t)f * UNITS + k]);
#pragma unroll
        for (int cc = 0; cc < 16; ++cc) acc[cc] += wd * Wl[f][cc];
    }
#pragma unroll
    for (int cc = 0; cc < 16; ++cc) {
        float uv = __bfloat162float(UTw[(size_t)(c0 + cc) * KWARM + k]);
        UTd[(size_t)(c0 + cc) * UNITS + k] = __float2bfloat16(uv + acc[cc]);
    }
}

__global__ __launch_bounds__(256) void build_bias(const float* __restrict__ b, const float* __restrict__ bd,
                                                  const __hip_bfloat16* __restrict__ UTw,
                                                  float* __restrict__ bw, float* __restrict__ bdc) {
    const int c = blockIdx.x * 256 + threadIdx.x;  // 16 blocks
    const int oc = (c & 3) * UNITS + (c >> 2);
    float base = b[oc];
    float s = 0.f;
    for (int f = 0; f < FEAT; ++f) s += bd[f] * __bfloat162float(UTw[(size_t)c * KWARM + UNITS + f]);
    bw[c] = base;
    bdc[c] = base + s;
}

__global__ void convert_x(const float* __restrict__ x, __hip_bfloat16* __restrict__ xb, int n) {
    int i = blockIdx.x * blockDim.x + threadIdx.x;
    if (i < n) xb[i] = __float2bfloat16(x[i]);
}

// ---------- fused LSTM step ----------
// Z[2048][4096(interleaved)] = [h | x_t] @ UT^T + bias ; gates -> c,h update in epilogue.
// PRED: nb==0 blocks also compute pred_{t} = h_in @ Wd + bd into out[:, tstep, :].
// R2: XOR-swizzled LDS (pre-swizzled global src + swizzled ds_read), double-buffered
//     2-phase pipeline with raw s_barrier + counted vmcnt (loads stay in flight).
template <bool WARM, bool PRED>
__global__ __launch_bounds__(256) void lstm_step(
    const __hip_bfloat16* __restrict__ hin,          // [2048][1024]
    const __hip_bfloat16* __restrict__ xbf, int t,   // [2048][48][64] (WARM only)
    const __hip_bfloat16* __restrict__ UT, int Kdim, // [4096][Kdim]
    const float* __restrict__ bias,                  // [4096]
    float* __restrict__ cst,                         // [2048][1024]
    __hip_bfloat16* __restrict__ hout,               // [2048][1024]
    const __hip_bfloat16* __restrict__ WdT,          // [64][1024] (PRED)
    const float* __restrict__ bd,                    // [64] (PRED)
    float* __restrict__ out, int tstep)              // [2048][64][64] (PRED)
{
    __shared__ alignas(16) __hip_bfloat16 Al[2][128 * 64];
    __shared__ alignas(16) __hip_bfloat16 Bl[2][128 * 64];
    __shared__ alignas(16) __hip_bfloat16 Wl[PRED ? 2 : 1][PRED ? 64 * 64 : 8];

    const int tid = threadIdx.x;
    const int lane = tid & 63;
    const int wv = tid >> 6;
    const int wr = wv >> 1, wc = wv & 1;
    const int bid = blockIdx.x;
    const int nb = bid & 31;   // 32 n-tiles
    const int mb = bid >> 5;   // 16 m-tiles
    const int m0 = mb * 128;
    const int n0 = nb * 128;
    const bool doPred = PRED && (nb == 0);

    f32x4 acc[4][4] = {};
    f32x4 accp[2][4] = {};

    const int nkt = Kdim >> 6;
    const int lrow = lane >> 3;                            // 0..7 row within 8-row chunk
    const int scol = ((lane & 7) * 16) ^ (lrow << 4);      // SWIZZLED source byte col (inverse swz on global side)

    // stage one 64-wide k-tile into buffer `buf`
    auto stage = [&](int buf, int kt) {
        const int k0 = kt * 64;
#pragma unroll
        for (int r = 0; r < 4; ++r) {
            int chunk = r * 4 + wv;
            int row = chunk * 8 + lrow;
            const char* src;
            if (WARM && k0 >= UNITS) {
                src = (const char*)xbf + (size_t)(m0 + row) * (T_IN * FEAT * 2) + (size_t)t * (FEAT * 2) + scol;
            } else {
                src = (const char*)hin + (size_t)(m0 + row) * (UNITS * 2) + (size_t)k0 * 2 + scol;
            }
            gl_lds16(src, (char*)&Al[buf][0] + chunk * 1024);
        }
#pragma unroll
        for (int r = 0; r < 4; ++r) {
            int chunk = r * 4 + wv;
            int row = chunk * 8 + lrow;
            const char* src = (const char*)UT + (size_t)(n0 + row) * ((size_t)Kdim * 2) + (size_t)k0 * 2 + scol;
            gl_lds16(src, (char*)&Bl[buf][0] + chunk * 1024);
        }
        if (PRED && doPred) {
#pragma unroll
            for (int r = 0; r < 2; ++r) {
                int chunk = r * 4 + wv;
                int row = chunk * 8 + lrow;
                const char* src = (const char*)WdT + (size_t)row * (UNITS * 2) + (size_t)k0 * 2 + scol;
                gl_lds16(src, (char*)&Wl[buf][0] + chunk * 1024);
            }
        }
    };

    const int ar = lane & 15;
    const int ko = (lane >> 4) << 3;
    const int swz = (ar & 7) << 3;   // element-index XOR for swizzled ds_read

    auto compute = [&](int buf) {
#pragma unroll
        for (int kk = 0; kk < 2; ++kk) {
            bf16x8 af[4], bfr[4];
#pragma unroll
            for (int mi = 0; mi < 4; ++mi)
                af[mi] = *reinterpret_cast<const bf16x8*>(&Al[buf][(64 * wr + 16 * mi + ar) * 64 + ((32 * kk + ko) ^ swz)]);
#pragma unroll
            for (int ni = 0; ni < 4; ++ni)
                bfr[ni] = *reinterpret_cast<const bf16x8*>(&Bl[buf][(64 * wc + 16 * ni + ar) * 64 + ((32 * kk + ko) ^ swz)]);
#pragma unroll
            for (int mi = 0; mi < 4; ++mi)
#pragma unroll
                for (int ni = 0; ni < 4; ++ni)
                    acc[mi][ni] = __builtin_amdgcn_mfma_f32_16x16x32_bf16(af[mi], bfr[ni], acc[mi][ni], 0, 0, 0);
            if (PRED && doPred) {
#pragma unroll
                for (int ni = 0; ni < 4; ++ni) {
                    bf16x8 bp = *reinterpret_cast<const bf16x8*>(&Wl[buf][(16 * ni + ar) * 64 + ((32 * kk + ko) ^ swz)]);
#pragma unroll
                    for (int pi = 0; pi < 2; ++pi)
                        accp[pi][ni] = __builtin_amdgcn_mfma_f32_16x16x32_bf16(af[2 * wc + pi], bp, accp[pi][ni], 0, 0, 0);
                }
            }
        }
    };

    // ---- pipelined K loop: prefetch kt+1 while computing kt; counted vmcnt ----
    int buf = 0;
    stage(0, 0);
    for (int kt = 0; kt < nkt - 1; ++kt) {
        stage(buf ^ 1, kt + 1);
        // wait only for the CURRENT buffer's loads (prev stage); keep next stage's in flight
        if (PRED && doPred) asm volatile("s_waitcnt vmcnt(10) lgkmcnt(0)" ::: "memory");
        else                asm volatile("s_waitcnt vmcnt(8) lgkmcnt(0)" ::: "memory");
        __builtin_amdgcn_s_barrier();
        compute(buf);
        __builtin_amdgcn_s_barrier();   // protect buf from being re-staged while slow waves read it
        buf ^= 1;
    }
    asm volatile("s_waitcnt vmcnt(0) lgkmcnt(0)" ::: "memory");
    __builtin_amdgcn_s_barrier();
    compute(buf);

    // ---- gate epilogue: cols interleaved 4u+gate; quad shuffle collects i,f,g,o ----
    const int g = lane & 3;
    const int rowb = m0 + 64 * wr + ((lane >> 4) << 2);
#pragma unroll
    for (int ni = 0; ni < 4; ++ni) {
        const int col = n0 + 64 * wc + 16 * ni + (lane & 15);
        const float bv = bias[col];
        const int unit = col >> 2;
#pragma unroll
        for (int mi = 0; mi < 4; ++mi) {
            f32x4 v = acc[mi][ni];
#pragma unroll
            for (int reg = 0; reg < 4; ++reg) {
                float z = v[reg] + bv;
                float z1 = __shfl_xor(z, 1);
                float z2 = __shfl_xor(z, 2);
                float z3 = __shfl_xor(z, 3);
                float zi, zf, zg, zo;
                if (g == 0)      { zi = z;  zf = z1; zg = z2; zo = z3; }
                else if (g == 1) { zi = z1; zf = z;  zg = z3; zo = z2; }
                else if (g == 2) { zi = z2; zf = z3; zg = z;  zo = z1; }
                else             { zi = z3; zf = z2; zg = z1; zo = z;  }
                if (g == reg) {
                    const size_t idx = (size_t)(rowb + 16 * mi + reg) * UNITS + unit;
                    float cn = sigm(zf) * cst[idx] + sigm(zi) * tanh_fast(zg);
                    cst[idx] = cn;
                    hout[idx] = __float2bfloat16(sigm(zo) * tanh_fast(cn));
                }
            }
        }
    }

    if (PRED && doPred) {
#pragma unroll
        for (int ni = 0; ni < 4; ++ni) {
            const int f = 16 * ni + (lane & 15);
            const float bdv = bd[f];
#pragma unroll
            for (int pi = 0; pi < 2; ++pi) {
                const int prow = m0 + 64 * wr + 32 * wc + 16 * pi + ((lane >> 4) << 2);
                f32x4 v = accp[pi][ni];
#pragma unroll
                for (int reg = 0; reg < 4; ++reg) {
                    out[(size_t)(prow + reg) * (OUT_STEPS * FEAT) + (size_t)tstep * FEAT + f] = v[reg] + bdv;
                }
            }
        }
    }
}

// ---------- host ----------
extern "C" void kernel_launch(void* const* d_in, const int* in_sizes, int n_in,
                              void* d_out, int out_size, void* d_ws, size_t ws_size,
                              hipStream_t stream) {
    const float* inputs = (const float*)d_in[0];
    const float* W  = (const float*)d_in[1];
    const float* U  = (const float*)d_in[2];
    const float* b  = (const float*)d_in[3];
    const float* Wd = (const float*)d_in[4];
    const float* bd = (const float*)d_in[5];
    float* out = (float*)d_out;

    char* ws = (char*)d_ws;
    size_t off = 0;
    auto alloc = [&](size_t bytes) { char* p = ws + off; off = (off + bytes + 255) & ~255ULL; return p; };
    __hip_bfloat16* UTw = (__hip_bfloat16*)alloc((size_t)GCOLS * KWARM * 2);
    __hip_bfloat16* UTd = (__hip_bfloat16*)alloc((size_t)GCOLS * UNITS * 2);
    __hip_bfloat16* WdT = (__hip_bfloat16*)alloc((size_t)FEAT * UNITS * 2);
    __hip_bfloat16* Xbf = (__hip_bfloat16*)alloc((size_t)B_SZ * T_IN * FEAT * 2);
    __hip_bfloat16* hA  = (__hip_bfloat16*)alloc((size_t)B_SZ * UNITS * 2);
    __hip_bfloat16* hB  = (__hip_bfloat16*)alloc((size_t)B_SZ * UNITS * 2);
    float* cst = (float*)alloc((size_t)B_SZ * UNITS * 4);
    float* bw  = (float*)alloc(GCOLS * 4);
    float* bdc = (float*)alloc(GCOLS * 4);

    hipMemsetAsync(cst, 0, (size_t)B_SZ * UNITS * 4, stream);
    hipMemsetAsync(hA, 0, (size_t)B_SZ * UNITS * 2, stream);

    dim3 blk(256);
    reorder_UW<<<dim3(17, 64), blk, 0, stream>>>(U, W, UTw);
    transpose_Wd<<<dim3(16), blk, 0, stream>>>(Wd, WdT);
    build_UTdec<<<dim3(4, 256), blk, 0, stream>>>(UTw, WdT, UTd);
    build_bias<<<dim3(16), blk, 0, stream>>>(b, bd, UTw, bw, bdc);
    {
        int n = B_SZ * T_IN * FEAT;
        convert_x<<<dim3((n + 255) / 256), blk, 0, stream>>>(inputs, Xbf, n);
    }

    const __hip_bfloat16* cur = hA;
    __hip_bfloat16* nxt = hB;
    for (int t = 0; t < T_IN; ++t) {
        lstm_step<true, false><<<dim3(512), blk, 0, stream>>>(cur, Xbf, t, UTw, KWARM, bw, cst, nxt,
                                                              nullptr, nullptr, nullptr, 0);
        __hip_bfloat16* tmp = (__hip_bfloat16*)cur; cur = nxt; nxt = tmp;
    }
    // decode: kernel t consumes h_{t-1} (writes pred_{t-1}) and produces h_t
    for (int t = 1; t <= OUT_STEPS; ++t) {
        lstm_step<false, true><<<dim3(512), blk, 0, stream>>>(cur, nullptr, 0, UTd, UNITS, bdc, cst, nxt,
                                                              WdT, bd, out, t - 1);
        __hip_bfloat16* tmp = (__hip_bfloat16*)cur; cur = nxt; nxt = tmp;
    }
}

// Round 3
// 5169.827 us; speedup vs baseline: 2.8065x; 1.6441x over previous
//
#include <hip/hip_runtime.h>
#include <hip/hip_bf16.h>

typedef float f32x4 __attribute__((ext_vector_type(4)));
typedef __bf16 bf16x8 __attribute__((ext_vector_type(8)));

#define B_SZ 2048
#define T_IN 48
#define FEAT 64
#define UNITS 1024
#define GCOLS 4096   // 4*UNITS
#define OUT_STEPS 64
#define KWARM 1088   // UNITS + FEAT

// Gate-major column permutation: c' = 64*Bk + 16*g + u  (Bk = 64-col half-block, g = gate, u = unit-low)
// original (Keras i,f,g,o) column: oc = g*1024 + (Bk*16 + u)
__device__ __forceinline__ int oc_of(int c) {
    return (((c >> 4) & 3) * UNITS) + ((c >> 6) * 16) + (c & 15);
}

typedef __attribute__((address_space(1))) const void gas_t;
typedef __attribute__((address_space(3))) void las_t;

__device__ __forceinline__ void gl_lds16(const void* g, void* l) {
    __builtin_amdgcn_global_load_lds((gas_t*)g, (las_t*)l, 16, 0, 0);
}
__device__ __forceinline__ float sigm(float x) {
    return __builtin_amdgcn_rcpf(1.0f + __expf(-x));
}
__device__ __forceinline__ float tanh_fast(float x) {
    float e = __expf(2.0f * x);
    return 1.0f - 2.0f * __builtin_amdgcn_rcpf(e + 1.0f);
}

// ---------- precompute kernels ----------

__global__ __launch_bounds__(256) void reorder_UW(const float* __restrict__ U, const float* __restrict__ W,
                                                  __hip_bfloat16* __restrict__ UTw) {
    __shared__ __hip_bfloat16 t[64][64];
    const int k0 = blockIdx.x * 64;   // 17 tiles
    const int c0 = blockIdx.y * 64;   // 64 tiles
    const int tid = threadIdx.x;
#pragma unroll
    for (int i = 0; i < 16; ++i) {
        int idx = tid + i * 256;
        int rk = idx >> 6, cc = idx & 63;
        int k = k0 + rk, c = c0 + cc;
        int oc = oc_of(c);
        float v = (k < UNITS) ? U[(size_t)k * GCOLS + oc] : W[(size_t)(k - UNITS) * GCOLS + oc];
        t[rk][cc] = __float2bfloat16(v);
    }
    __syncthreads();
#pragma unroll
    for (int i = 0; i < 16; ++i) {
        int idx = tid + i * 256;
        int rc = idx >> 6, kk = idx & 63;
        UTw[(size_t)(c0 + rc) * KWARM + k0 + kk] = t[kk][rc];
    }
}

__global__ __launch_bounds__(256) void transpose_Wd(const float* __restrict__ Wd, __hip_bfloat16* __restrict__ WdT) {
    __shared__ __hip_bfloat16 t[64][64];
    const int k0 = blockIdx.x * 64;  // 16 blocks
    const int tid = threadIdx.x;
#pragma unroll
    for (int i = 0; i < 16; ++i) {
        int idx = tid + i * 256;
        int rk = idx >> 6, ff = idx & 63;
        t[rk][ff] = __float2bfloat16(Wd[(size_t)(k0 + rk) * FEAT + ff]);
    }
    __syncthreads();
#pragma unroll
    for (int i = 0; i < 16; ++i) {
        int idx = tid + i * 256;
        int rf = idx >> 6, kk = idx & 63;
        WdT[(size_t)rf * UNITS + k0 + kk] = t[kk][rf];
    }
}

__global__ __launch_bounds__(256) void build_UTdec(const __hip_bfloat16* __restrict__ UTw,
                                                   const __hip_bfloat16* __restrict__ WdT,
                                                   __hip_bfloat16* __restrict__ UTd) {
    __shared__ float Wl[64][16];
    const int k = blockIdx.x * 256 + threadIdx.x;  // 4 blocks
    const int c0 = blockIdx.y * 16;                // 256 blocks
    const int tid = threadIdx.x;
#pragma unroll
    for (int i = 0; i < 4; ++i) {
        int idx = tid + i * 256;
        int f = idx >> 4, cc = idx & 15;
        Wl[f][cc] = __bfloat162float(UTw[(size_t)(c0 + cc) * KWARM + UNITS + f]);
    }
    __syncthreads();
    float acc[16];
#pragma unroll
    for (int cc = 0; cc < 16; ++cc) acc[cc] = 0.f;
    for (int f = 0; f < 64; ++f) {
        float wd = __bfloat162float(WdT[(size_t)f * UNITS + k]);
#pragma unroll
        for (int cc = 0; cc < 16; ++cc) acc[cc] += wd * Wl[f][cc];
    }
#pragma unroll
    for (int cc = 0; cc < 16; ++cc) {
        float uv = __bfloat162float(UTw[(size_t)(c0 + cc) * KWARM + k]);
        UTd[(size_t)(c0 + cc) * UNITS + k] = __float2bfloat16(uv + acc[cc]);
    }
}

__global__ __launch_bounds__(256) void build_bias(const float* __restrict__ b, const float* __restrict__ bd,
                                                  const __hip_bfloat16* __restrict__ UTw,
                                                  float* __restrict__ bw, float* __restrict__ bdc) {
    const int c = blockIdx.x * 256 + threadIdx.x;  // 16 blocks
    const int oc = oc_of(c);
    float base = b[oc];
    float s = 0.f;
    for (int f = 0; f < FEAT; ++f) s += bd[f] * __bfloat162float(UTw[(size_t)c * KWARM + UNITS + f]);
    bw[c] = base;
    bdc[c] = base + s;
}

__global__ void convert_x(const float* __restrict__ x, __hip_bfloat16* __restrict__ xb, int n) {
    int i = blockIdx.x * blockDim.x + threadIdx.x;
    if (i < n) xb[i] = __float2bfloat16(x[i]);
}

// ---------- fused LSTM step ----------
// R3: compile-time K (full unroll, imm-offset staging), gate-major columns
// (shuffle-free epilogue, coalesced c/h stores), XCD mb-grouped swizzle,
// c-state prefetch under final MFMA phase.
template <bool WARM, bool PRED>
__global__ __launch_bounds__(256) void lstm_step(
    const __hip_bfloat16* __restrict__ hin,          // [2048][1024]
    const __hip_bfloat16* __restrict__ xbf, int t,   // [2048][48][64] (WARM)
    const __hip_bfloat16* __restrict__ UT,           // [4096][KD]
    const float* __restrict__ bias,                  // [4096] (c'-indexed)
    float* __restrict__ cst,                         // [2048][1024]
    __hip_bfloat16* __restrict__ hout,               // [2048][1024]
    const __hip_bfloat16* __restrict__ WdT,          // [64][1024] (PRED)
    const float* __restrict__ bd,                    // [64] (PRED)
    float* __restrict__ out, int tstep)              // [2048][64][64] (PRED)
{
    constexpr int KD = WARM ? KWARM : UNITS;
    constexpr int NKT = KD / 64;

    __shared__ alignas(16) __hip_bfloat16 Al[2 * 8192];
    __shared__ alignas(16) __hip_bfloat16 Bl[2 * 8192];
    __shared__ alignas(16) __hip_bfloat16 Wl[PRED ? 2 * 4096 : 8];

    const int tid = threadIdx.x;
    const int lane = tid & 63;
    const int wv = tid >> 6;
    const int wr = wv >> 1, wc = wv & 1;
    const int bid = blockIdx.x;
    // XCD-aware: xcd = bid&7 owns mb {2*xcd, 2*xcd+1}; adjacent dispatches share nb
    const int xcd = bid & 7;
    const int i6 = bid >> 3;
    const int mb = xcd * 2 + (i6 & 1);
    const int nb = i6 >> 1;
    const int m0 = mb * 128;
    const int n0 = nb * 128;
    const bool doPred = PRED && (nb == 0);

    f32x4 acc[4][4] = {};
    f32x4 accp[2][4] = {};

    const int lrow = lane >> 3;
    const int scol = ((lane & 7) * 16) ^ (lrow << 4);   // swizzled source byte col

    // loop-invariant global source bases (k-advance folds into imm offsets)
    const char* aS[4]; const char* bS[4]; const char* xS[4]; const char* wS[2];
#pragma unroll
    for (int r = 0; r < 4; ++r) {
        int row = (r * 4 + wv) * 8 + lrow;
        aS[r] = (const char*)hin + (size_t)(m0 + row) * (UNITS * 2) + scol;
        bS[r] = (const char*)UT + (size_t)(n0 + row) * (KD * 2) + scol;
        if (WARM) xS[r] = (const char*)xbf + (size_t)(m0 + row) * (T_IN * FEAT * 2) + (size_t)t * (FEAT * 2) + scol;
    }
    if (PRED && doPred) {
#pragma unroll
        for (int r = 0; r < 2; ++r) {
            int row = (r * 4 + wv) * 8 + lrow;
            wS[r] = (const char*)WdT + (size_t)row * (UNITS * 2) + scol;
        }
    }

    // epilogue geometry; bias preloaded early (retired by first counted vmcnt)
    const int u16 = lane & 15;
    const int unit = (nb * 2 + wc) * 16 + u16;
    const int rbase = m0 + 64 * wr + ((lane >> 4) << 2);
    float bv[4];
#pragma unroll
    for (int g = 0; g < 4; ++g) bv[g] = bias[n0 + 64 * wc + 16 * g + u16];
    float bdv[4];
    if (PRED && doPred) {
#pragma unroll
        for (int ni = 0; ni < 4; ++ni) bdv[ni] = bd[16 * ni + u16];
    }

    auto stage = [&](int kt) {
        const int buf = kt & 1;
#pragma unroll
        for (int r = 0; r < 4; ++r) {
            const char* s = (WARM && kt == NKT - 1) ? xS[r] : (aS[r] + kt * 128);
            gl_lds16(s, (char*)Al + buf * 16384 + (r * 4 + wv) * 1024);
        }
#pragma unroll
        for (int r = 0; r < 4; ++r)
            gl_lds16(bS[r] + kt * 128, (char*)Bl + buf * 16384 + (r * 4 + wv) * 1024);
        if (PRED && doPred) {
#pragma unroll
            for (int r = 0; r < 2; ++r)
                gl_lds16(wS[r] + kt * 128, (char*)Wl + buf * 8192 + (r * 4 + wv) * 1024);
        }
    };

    const int ar = lane & 15;
    const int ko = (lane >> 4) << 3;
    const int swz = (ar & 7) << 3;

    auto compute = [&](int kt) {
        const int buf = kt & 1;
#pragma unroll
        for (int kk = 0; kk < 2; ++kk) {
            bf16x8 af[4], bfr[4];
#pragma unroll
            for (int mi = 0; mi < 4; ++mi)
                af[mi] = *reinterpret_cast<const bf16x8*>(&Al[buf * 8192 + (64 * wr + 16 * mi + ar) * 64 + ((32 * kk + ko) ^ swz)]);
#pragma unroll
            for (int ni = 0; ni < 4; ++ni)
                bfr[ni] = *reinterpret_cast<const bf16x8*>(&Bl[buf * 8192 + (64 * wc + 16 * ni + ar) * 64 + ((32 * kk + ko) ^ swz)]);
#pragma unroll
            for (int mi = 0; mi < 4; ++mi)
#pragma unroll
                for (int ni = 0; ni < 4; ++ni)
                    acc[mi][ni] = __builtin_amdgcn_mfma_f32_16x16x32_bf16(af[mi], bfr[ni], acc[mi][ni], 0, 0, 0);
            if (PRED && doPred) {
#pragma unroll
                for (int ni = 0; ni < 4; ++ni) {
                    bf16x8 bp = *reinterpret_cast<const bf16x8*>(&Wl[buf * 4096 + (16 * ni + ar) * 64 + ((32 * kk + ko) ^ swz)]);
#pragma unroll
                    for (int pi = 0; pi < 2; ++pi)
                        accp[pi][ni] = __builtin_amdgcn_mfma_f32_16x16x32_bf16(af[2 * wc + pi], bp, accp[pi][ni], 0, 0, 0);
                }
            }
        }
    };

    // ---- fully-unrolled pipelined K loop ----
    stage(0);
#pragma unroll
    for (int kt = 0; kt < NKT - 1; ++kt) {
        stage(kt + 1);
        if (PRED && doPred) asm volatile("s_waitcnt vmcnt(10) lgkmcnt(0)" ::: "memory");
        else                asm volatile("s_waitcnt vmcnt(8) lgkmcnt(0)" ::: "memory");
        __builtin_amdgcn_s_barrier();
        compute(kt);
        __builtin_amdgcn_s_barrier();
    }
    // prefetch c-state; its latency hides under the final MFMA phase
    float cv[16];
#pragma unroll
    for (int mi = 0; mi < 4; ++mi)
#pragma unroll
        for (int reg = 0; reg < 4; ++reg)
            cv[mi * 4 + reg] = cst[(size_t)(rbase + 16 * mi + reg) * UNITS + unit];
    asm volatile("s_waitcnt vmcnt(16) lgkmcnt(0)" ::: "memory");
    __builtin_amdgcn_s_barrier();
    compute(NKT - 1);

    // ---- shuffle-free gate epilogue: acc[mi][g] are i,f,g,o of this lane's unit ----
#pragma unroll
    for (int mi = 0; mi < 4; ++mi)
#pragma unroll
        for (int reg = 0; reg < 4; ++reg) {
            float zi = acc[mi][0][reg] + bv[0];
            float zf = acc[mi][1][reg] + bv[1];
            float zg = acc[mi][2][reg] + bv[2];
            float zo = acc[mi][3][reg] + bv[3];
            float cn = sigm(zf) * cv[mi * 4 + reg] + sigm(zi) * tanh_fast(zg);
            size_t idx = (size_t)(rbase + 16 * mi + reg) * UNITS + unit;
            cst[idx] = cn;
            hout[idx] = __float2bfloat16(sigm(zo) * tanh_fast(cn));
        }

    if (PRED && doPred) {
#pragma unroll
        for (int ni = 0; ni < 4; ++ni) {
#pragma unroll
            for (int pi = 0; pi < 2; ++pi) {
                const int prow = m0 + 64 * wr + 32 * wc + 16 * pi + ((lane >> 4) << 2);
                f32x4 v = accp[pi][ni];
#pragma unroll
                for (int reg = 0; reg < 4; ++reg)
                    out[(size_t)(prow + reg) * (OUT_STEPS * FEAT) + (size_t)tstep * FEAT + (16 * ni + u16)] = v[reg] + bdv[ni];
            }
        }
    }
}

// ---------- host ----------
extern "C" void kernel_launch(void* const* d_in, const int* in_sizes, int n_in,
                              void* d_out, int out_size, void* d_ws, size_t ws_size,
                              hipStream_t stream) {
    const float* inputs = (const float*)d_in[0];
    const float* W  = (const float*)d_in[1];
    const float* U  = (const float*)d_in[2];
    const float* b  = (const float*)d_in[3];
    const float* Wd = (const float*)d_in[4];
    const float* bd = (const float*)d_in[5];
    float* out = (float*)d_out;

    char* ws = (char*)d_ws;
    size_t off = 0;
    auto alloc = [&](size_t bytes) { char* p = ws + off; off = (off + bytes + 255) & ~255ULL; return p; };
    __hip_bfloat16* UTw = (__hip_bfloat16*)alloc((size_t)GCOLS * KWARM * 2);
    __hip_bfloat16* UTd = (__hip_bfloat16*)alloc((size_t)GCOLS * UNITS * 2);
    __hip_bfloat16* WdT = (__hip_bfloat16*)alloc((size_t)FEAT * UNITS * 2);
    __hip_bfloat16* Xbf = (__hip_bfloat16*)alloc((size_t)B_SZ * T_IN * FEAT * 2);
    __hip_bfloat16* hA  = (__hip_bfloat16*)alloc((size_t)B_SZ * UNITS * 2);
    __hip_bfloat16* hB  = (__hip_bfloat16*)alloc((size_t)B_SZ * UNITS * 2);
    float* cst = (float*)alloc((size_t)B_SZ * UNITS * 4);
    float* bw  = (float*)alloc(GCOLS * 4);
    float* bdc = (float*)alloc(GCOLS * 4);

    hipMemsetAsync(cst, 0, (size_t)B_SZ * UNITS * 4, stream);
    hipMemsetAsync(hA, 0, (size_t)B_SZ * UNITS * 2, stream);

    dim3 blk(256);
    reorder_UW<<<dim3(17, 64), blk, 0, stream>>>(U, W, UTw);
    transpose_Wd<<<dim3(16), blk, 0, stream>>>(Wd, WdT);
    build_UTdec<<<dim3(4, 256), blk, 0, stream>>>(UTw, WdT, UTd);
    build_bias<<<dim3(16), blk, 0, stream>>>(b, bd, UTw, bw, bdc);
    {
        int n = B_SZ * T_IN * FEAT;
        convert_x<<<dim3((n + 255) / 256), blk, 0, stream>>>(inputs, Xbf, n);
    }

    const __hip_bfloat16* cur = hA;
    __hip_bfloat16* nxt = hB;
    for (int t = 0; t < T_IN; ++t) {
        lstm_step<true, false><<<dim3(512), blk, 0, stream>>>(cur, Xbf, t, UTw, bw, cst, nxt,
                                                              nullptr, nullptr, nullptr, 0);
        __hip_bfloat16* tmp = (__hip_bfloat16*)cur; cur = nxt; nxt = tmp;
    }
    // decode: kernel t consumes h_{t-1} (writes pred_{t-1}) and produces h_t
    for (int t = 1; t <= OUT_STEPS; ++t) {
        lstm_step<false, true><<<dim3(512), blk, 0, stream>>>(cur, nullptr, 0, UTd, bdc, cst, nxt,
                                                              WdT, bd, out, t - 1);
        __hip_bfloat16* tmp = (__hip_bfloat16*)cur; cur = nxt; nxt = tmp;
    }
}